// Round 1
// baseline (258.940 us; speedup 1.0000x reference)
//
#include <hip/hip_runtime.h>
#include <hip/hip_bf16.h>

#define M_DIM 32
#define K_DIM 4096
#define N_DIM 11008
#define GS 128
#define BN 64          // output columns per block (4 waves x 16)
#define BK 512         // k-extent per block (4 quant groups)
#define KSPLIT (K_DIM / BK)   // 8
#define LDS_STRIDE (BK + 8)   // bf16 elements; +8 (16B) pad breaks 16-way bank conflict

typedef __attribute__((ext_vector_type(8))) short short8;
typedef __attribute__((ext_vector_type(4))) float floatx4;

__device__ inline unsigned short f2bf(float f) {
    unsigned u = __builtin_bit_cast(unsigned, f);
    u += 0x7fffu + ((u >> 16) & 1u);   // round-to-nearest-even
    return (unsigned short)(u >> 16);
}

__global__ __launch_bounds__(256, 4) void int4mm_kernel(
    const float* __restrict__ x,      // [32, 4096] fp32
    const int*   __restrict__ q,      // [11008, 4096] int32 in [0,16)
    const float* __restrict__ sz,     // [32, 11008, 2] fp32 (scale, zero)
    float*       __restrict__ out)    // [32, 11008] fp32, pre-zeroed
{
    __shared__ unsigned short shx[M_DIM * LDS_STRIDE];

    const int tid  = threadIdx.x;
    const int wave = tid >> 6;
    const int lane = tid & 63;
    const int nblk = blockIdx.x;
    const int kc   = blockIdx.y * BK;

    // ---- stage x[0:32][kc:kc+BK] into LDS as bf16 (coalesced float4 loads) ----
    for (int idx = tid * 4; idx < M_DIM * BK; idx += 256 * 4) {
        const int r = idx >> 9;          // idx / 512
        const int c = idx & (BK - 1);    // idx % 512
        const float4 v = *(const float4*)(x + (long)r * K_DIM + kc + c);
        unsigned short* p = &shx[r * LDS_STRIDE + c];
        p[0] = f2bf(v.x); p[1] = f2bf(v.y); p[2] = f2bf(v.z); p[3] = f2bf(v.w);
    }
    __syncthreads();

    const int nlo = lane & 15;           // column within wave tile / A-row m
    const int kq  = lane >> 4;           // k-quad for A/B fragments
    const int ng  = nblk * BN + wave * 16 + nlo;   // this lane's output column
    const long qbase = (long)ng * K_DIM + kc + kq * 8;

    floatx4 acc0 = {0.f, 0.f, 0.f, 0.f};   // rows 0..15
    floatx4 acc1 = {0.f, 0.f, 0.f, 0.f};   // rows 16..31

    const int g0 = kc / GS;
    #pragma unroll 1
    for (int gi = 0; gi < BK / GS; ++gi) {   // 4 quant groups per chunk
        const float2 sv = *(const float2*)(sz + ((long)(g0 + gi) * N_DIM + ng) * 2);
        const float s  = sv.x;
        const float c0 = sv.y - 8.0f * s;    // w = q*s + (z - 8s)

        // issue all q loads for this group's 4 k-steps (8x dwordx4 in flight)
        int4 qa[4], qb[4];
        #pragma unroll
        for (int t = 0; t < 4; ++t) {
            const int* qp = q + qbase + gi * GS + t * 32;
            qa[t] = *(const int4*)(qp);
            qb[t] = *(const int4*)(qp + 4);
        }

        #pragma unroll
        for (int t = 0; t < 4; ++t) {
            // B fragment: 8 dequantized bf16 weights for k = kq*8 + 0..7
            short8 b;
            b[0] = (short)f2bf(fmaf((float)qa[t].x, s, c0));
            b[1] = (short)f2bf(fmaf((float)qa[t].y, s, c0));
            b[2] = (short)f2bf(fmaf((float)qa[t].z, s, c0));
            b[3] = (short)f2bf(fmaf((float)qa[t].w, s, c0));
            b[4] = (short)f2bf(fmaf((float)qb[t].x, s, c0));
            b[5] = (short)f2bf(fmaf((float)qb[t].y, s, c0));
            b[6] = (short)f2bf(fmaf((float)qb[t].z, s, c0));
            b[7] = (short)f2bf(fmaf((float)qb[t].w, s, c0));

            // A fragments from LDS: x rows (m = nlo) and (m = 16+nlo)
            const int kL = gi * GS + t * 32 + kq * 8;
            const short8 a0 = *(const short8*)&shx[nlo * LDS_STRIDE + kL];
            const short8 a1 = *(const short8*)&shx[(16 + nlo) * LDS_STRIDE + kL];

            acc0 = __builtin_amdgcn_mfma_f32_16x16x32_bf16(a0, b, acc0, 0, 0, 0);
            acc1 = __builtin_amdgcn_mfma_f32_16x16x32_bf16(a1, b, acc1, 0, 0, 0);
        }
    }

    // ---- epilogue: k-split partials combined via fp32 atomics ----
    const int mrow = kq * 4;    // C/D layout: row = (lane>>4)*4 + reg, col = lane&15
    #pragma unroll
    for (int r = 0; r < 4; ++r) {
        atomicAdd(out + (long)(mrow + r) * N_DIM + ng, acc0[r]);
        atomicAdd(out + (long)(16 + mrow + r) * N_DIM + ng, acc1[r]);
    }
}

extern "C" void kernel_launch(void* const* d_in, const int* in_sizes, int n_in,
                              void* d_out, int out_size, void* d_ws, size_t ws_size,
                              hipStream_t stream) {
    const float* x  = (const float*)d_in[0];
    const int*   q  = (const int*)d_in[1];
    const float* sz = (const float*)d_in[2];
    float* out = (float*)d_out;

    // harness poisons d_out with 0xAA before every timed replay — zero it first
    hipMemsetAsync(d_out, 0, (size_t)M_DIM * N_DIM * sizeof(float), stream);

    dim3 grid(N_DIM / BN, KSPLIT);
    int4mm_kernel<<<grid, 256, 0, stream>>>(x, q, sz, out);
}